// Round 5
// baseline (474.735 us; speedup 1.0000x reference)
//
#include <hip/hip_runtime.h>
#include <math.h>

// Problem constants
#define T_SEQ 2048
#define D_MODEL 3072
#define NQ 16
#define NKV 8
#define HD 256
#define NHEADS_TOT 32
#define QKV_COLS 8192
#define SOFT_CAP 50.0f
#define WINDOW 1024
#define K_MASK -2.3819763e38f

typedef __attribute__((ext_vector_type(8))) short bf16x8;
typedef __attribute__((ext_vector_type(4))) float f32x4;

__device__ __forceinline__ unsigned short f2bf(float f) {
    union { float f; unsigned u; } v; v.f = f;
    unsigned r = (v.u + 0x7fff + ((v.u >> 16) & 1)) >> 16;
    return (unsigned short)r;
}
__device__ __forceinline__ float bf2f(unsigned short u) {
    union { unsigned u; float f; } v; v.u = ((unsigned)u) << 16;
    return v.f;
}

__device__ __forceinline__ void gl_lds16(const unsigned short* g, unsigned short* l) {
    __builtin_amdgcn_global_load_lds(
        (const __attribute__((address_space(1))) void*)g,
        (__attribute__((address_space(3))) void*)l, 16, 0, 0);
}

// ---------------- convert f32 -> bf16 (flat) ----------------
__global__ __launch_bounds__(256) void k_convert(const float* __restrict__ src,
                                                 unsigned short* __restrict__ dst, int n4) {
    int i = blockIdx.x * 256 + threadIdx.x;
    if (i >= n4) return;
    float4 v = ((const float4*)src)[i];
    ushort4 o;
    o.x = f2bf(v.x); o.y = f2bf(v.y); o.z = f2bf(v.z); o.w = f2bf(v.w);
    ((ushort4*)dst)[i] = o;
}

// ---------------- batched transpose+convert v2: (batch,R,C) f32 -> (batch,C,R) bf16 --------
// 64x64 tile, 256 threads.  Coalesced float4 reads, convert in reg, transposed LDS tile,
// coalesced ushort4 writes.  Requires R%64==C%64==0.
__global__ __launch_bounds__(256) void k_transpose_bf16(const float* __restrict__ src,
                                                        unsigned short* __restrict__ dst,
                                                        int R, int C) {
    __shared__ unsigned short T[64][68];   // [src-col][src-row], pad 4 to break banks
    int b = blockIdx.z;
    src += (size_t)b * R * C;
    dst += (size_t)b * R * C;
    int c0 = blockIdx.x * 64, r0 = blockIdx.y * 64;
    int tid = threadIdx.x;
    int wv = tid >> 6, ln = tid & 63;
    int rsub = (wv << 2) + (ln >> 4);      // 0..15
    int cq = (ln & 15) << 2;               // 0,4,...,60
    #pragma unroll
    for (int p = 0; p < 4; p++) {
        int row = p * 16 + rsub;
        float4 v = *(const float4*)&src[(size_t)(r0 + row) * C + c0 + cq];
        T[cq + 0][row] = f2bf(v.x);
        T[cq + 1][row] = f2bf(v.y);
        T[cq + 2][row] = f2bf(v.z);
        T[cq + 3][row] = f2bf(v.w);
    }
    __syncthreads();
    #pragma unroll
    for (int q = 0; q < 4; q++) {
        int crow = q * 16 + rsub;          // output row = global col c0+crow
        ushort4 o = *(const ushort4*)&T[crow][cq];
        *(ushort4*)&dst[(size_t)(c0 + crow) * R + r0 + cq] = o;
    }
}

// ---------------- RoPE trig table: (T, 128) float2 {sin, cos} ----------------
__global__ __launch_bounds__(128) void k_trig(const int* __restrict__ spos,
                                              float2* __restrict__ tbl) {
    int t = blockIdx.x, hh = threadIdx.x;
    float fr = (float)hh * (1.0f / 128.0f);
    float ts = __expf(fr * 9.210340371976184f);   // 10000^fr
    float ang = (float)spos[t] / ts;
    float2 sc;
    sc.x = __sinf(ang);
    sc.y = __cosf(ang);
    tbl[(size_t)t * 128 + hh] = sc;
}

// ---------------- gemm1 + fused RMS-norm/RoPE/V-transpose epilogue ----------------
// C = A * BT^T over 128x256 tiles; each block's 256 cols = exactly ONE head slot
// (slot = n0/256: 0-15 q, 16-23 k, 24-31 v).  RMS-norm over H=256 = block cols, computed
// on the f32 accumulators (closer to f32 reference than the old bf16 qkv round-trip).
// Epilogue: per-row sum via shfl_xor(16) + LDS combine across the 2 col-half waves;
// RoPE pair (h,h+128) = (wc0,wc1) exchanged through dead Bs in 4 chunks of 16 rows;
// v written directly transposed into vT.  Replaces k_norm_rope + k_transpose_v and the
// 33.5 MB qkv round-trip.  MFMA loop identical to the R0-proven structure.
__global__ __launch_bounds__(256, 2) void k_gemm1(const unsigned short* __restrict__ A,
                                                  const unsigned short* __restrict__ BT,
                                                  const float2* __restrict__ trig,
                                                  const float* __restrict__ qscale,
                                                  const float* __restrict__ kscale,
                                                  unsigned short* __restrict__ qh,
                                                  unsigned short* __restrict__ kh,
                                                  unsigned short* __restrict__ vT,
                                                  int M, int N, int Kd) {
    __shared__ unsigned short As[128 * 64];   // 16 KB
    __shared__ unsigned short Bs[256 * 64];   // 32 KB
    const int tid = threadIdx.x;
    const int wave = tid >> 6, lane = tid & 63;
    const int col = lane & 15, quad = lane >> 4;
    const int wr = wave & 1, wc = wave >> 1;

    int p = blockIdx.x;                 // 512 blocks
    int xcd = p & 7, q = p >> 3;        // q in [0,64)
    int i_t = q & 15, jj = q >> 4;      // i in [0,16), jj in [0,4)
    const int m0 = i_t * 128, n0 = (jj * 8 + xcd) * 256;

    const int lrow = lane >> 3, lchk = lane & 7;
    int soffA[4], soffB[8];
    #pragma unroll
    for (int s = 0; s < 4; s++) {
        int r = wave * 32 + s * 8 + lrow;
        soffA[s] = r * Kd + ((lchk ^ (r & 7)) * 8);
    }
    #pragma unroll
    for (int s = 0; s < 8; s++) {
        int r = wave * 64 + s * 8 + lrow;
        soffB[s] = r * Kd + ((lchk ^ (r & 7)) * 8);
    }
    const unsigned short* Ab = A + (size_t)m0 * Kd;
    const unsigned short* Bb = BT + (size_t)n0 * Kd;

    f32x4 acc[4][8];
    #pragma unroll
    for (int i = 0; i < 4; i++)
        #pragma unroll
        for (int j = 0; j < 8; j++)
            acc[i][j] = (f32x4){0.f, 0.f, 0.f, 0.f};

    const int sw = col & 7;

    for (int k0 = 0; k0 < Kd; k0 += 64) {
        #pragma unroll
        for (int s = 0; s < 4; s++)
            gl_lds16(Ab + soffA[s] + k0, &As[(wave * 32 + s * 8) * 64]);
        #pragma unroll
        for (int s = 0; s < 8; s++)
            gl_lds16(Bb + soffB[s] + k0, &Bs[(wave * 64 + s * 8) * 64]);
        __syncthreads();

        #pragma unroll
        for (int kk = 0; kk < 2; kk++) {
            const int chko = ((kk * 4 + quad) ^ sw) * 8;
            bf16x8 af[4];
            #pragma unroll
            for (int i = 0; i < 4; i++)
                af[i] = *(const bf16x8*)&As[(wr * 64 + i * 16 + col) * 64 + chko];
            #pragma unroll
            for (int j = 0; j < 8; j++) {
                bf16x8 bfr = *(const bf16x8*)&Bs[(wc * 128 + j * 16 + col) * 64 + chko];
                #pragma unroll
                for (int i = 0; i < 4; i++)
                    acc[i][j] = __builtin_amdgcn_mfma_f32_16x16x32_bf16(af[i], bfr, acc[i][j], 0, 0, 0);
            }
        }
        __syncthreads();
    }

    // ================= fused epilogue =================
    const int slot = n0 >> 8;              // block-uniform: 0-15 q, 16-23 k, 24-31 v
    float* rs = (float*)As;                // [2][128] row sums per col-half

    // (a) per-row sum of squares: lane partial (8 cols) -> 16-lane col-group reduce
    float rinv[4][4];
    #pragma unroll
    for (int i = 0; i < 4; i++)
        #pragma unroll
        for (int r = 0; r < 4; r++) {
            float ss = 0.f;
            #pragma unroll
            for (int j = 0; j < 8; j++) ss += acc[i][j][r] * acc[i][j][r];
            #pragma unroll
            for (int m = 1; m < 16; m <<= 1) ss += __shfl_xor(ss, m, 16);
            if (col == 0) rs[wc * 128 + wr * 64 + i * 16 + quad * 4 + r] = ss;
        }
    __syncthreads();
    #pragma unroll
    for (int i = 0; i < 4; i++)
        #pragma unroll
        for (int r = 0; r < 4; r++) {
            int rl = wr * 64 + i * 16 + quad * 4 + r;
            float tot = rs[rl] + rs[128 + rl];
            rinv[i][r] = rsqrtf(tot * (1.0f / 256.0f) + 1e-6f);
        }

    // (b) per-col scale factor
    float scl[8];
    #pragma unroll
    for (int j = 0; j < 8; j++) {
        int h = wc * 128 + j * 16 + col;
        scl[j] = (slot < 16) ? (1.0f + qscale[h])
               : (slot < 24) ? (1.0f + kscale[h]) : 1.0f;
    }

    // (c) 4 chunks of 16 rows: y -> LDS exchange (RoPE partner lives in the other
    // col-half wave) -> rope -> store.  yb = [wc][wr][16 rows][128 cols] f32 = 32 KB = Bs.
    float* yb = (float*)Bs;
    #pragma unroll
    for (int i = 0; i < 4; i++) {
        float yv[8][4];
        #pragma unroll
        for (int j = 0; j < 8; j++)
            #pragma unroll
            for (int r = 0; r < 4; r++)
                yv[j][r] = acc[i][j][r] * rinv[i][r] * scl[j];
        #pragma unroll
        for (int j = 0; j < 8; j++)
            #pragma unroll
            for (int r = 0; r < 4; r++)
                yb[((wc * 2 + wr) * 16 + quad * 4 + r) * 128 + j * 16 + col] = yv[j][r];
        __syncthreads();
        #pragma unroll
        for (int j = 0; j < 8; j++) {
            int h = wc * 128 + j * 16 + col;
            #pragma unroll
            for (int r = 0; r < 4; r++) {
                int t = m0 + wr * 64 + i * 16 + quad * 4 + r;
                float oth = yb[(((wc ^ 1) * 2 + wr) * 16 + quad * 4 + r) * 128 + j * 16 + col];
                float outv;
                if (slot < 24) {
                    float2 sc = trig[(size_t)t * 128 + j * 16 + col];
                    outv = (wc == 0) ? (yv[j][r] * sc.y - oth * sc.x)
                                     : (yv[j][r] * sc.y + oth * sc.x);
                } else {
                    outv = yv[j][r];
                }
                if (slot < 16)
                    qh[((size_t)slot * T_SEQ + t) * HD + h] = f2bf(outv);
                else if (slot < 24)
                    kh[((size_t)(slot - 16) * T_SEQ + t) * HD + h] = f2bf(outv);
                else
                    vT[((size_t)(slot - 24) * HD + h) * T_SEQ + t] = f2bf(outv);
            }
        }
        __syncthreads();
    }
}

// ---------------- gemm2: 128x64 tile, BK=128 (32 barriers), 768 blocks, f32 out ----------------
__global__ __launch_bounds__(256) void k_gemm2(const unsigned short* __restrict__ A,
                                               const unsigned short* __restrict__ BT,
                                               float* __restrict__ C,
                                               int M, int N, int Kd) {
    __shared__ unsigned short As[128 * 128];  // 32 KB
    __shared__ unsigned short Bs[64 * 128];   // 16 KB
    const int tid = threadIdx.x;
    const int wave = tid >> 6, lane = tid & 63;
    const int col = lane & 15, quad = lane >> 4;

    int p = blockIdx.x;                    // 768 blocks
    int xcd = p & 7, q = p >> 3;           // q in [0,96)
    int i_t = q % 16, jj = q / 16;         // jj in [0,6)
    const int m0 = i_t * 128, n0 = (jj * 8 + xcd) * 64;

    const int lrow = lane >> 4, lchk = lane & 15;
    int soffA[8], soffB[4];
    #pragma unroll
    for (int s = 0; s < 8; s++) {
        int r = wave * 32 + s * 4 + lrow;
        soffA[s] = r * Kd + ((lchk ^ (r & 7)) * 8);
    }
    #pragma unroll
    for (int s = 0; s < 4; s++) {
        int r = wave * 16 + s * 4 + lrow;
        soffB[s] = r * Kd + ((lchk ^ (r & 7)) * 8);
    }
    const unsigned short* Ab = A + (size_t)m0 * Kd;
    const unsigned short* Bb = BT + (size_t)n0 * Kd;

    f32x4 acc[2][4];
    #pragma unroll
    for (int i = 0; i < 2; i++)
        #pragma unroll
        for (int j = 0; j < 4; j++)
            acc[i][j] = (f32x4){0.f, 0.f, 0.f, 0.f};

    const int sw = col & 7;

    for (int k0 = 0; k0 < Kd; k0 += 128) {
        #pragma unroll
        for (int s = 0; s < 8; s++)
            gl_lds16(Ab + soffA[s] + k0, &As[(wave * 32 + s * 4) * 128]);
        #pragma unroll
        for (int s = 0; s < 4; s++)
            gl_lds16(Bb + soffB[s] + k0, &Bs[(wave * 16 + s * 4) * 128]);
        __syncthreads();

        #pragma unroll
        for (int kk = 0; kk < 4; kk++) {
            const int chko = ((kk * 4 + quad) ^ sw) * 8;
            bf16x8 af[2], bfr[4];
            #pragma unroll
            for (int i = 0; i < 2; i++)
                af[i] = *(const bf16x8*)&As[(wave * 32 + i * 16 + col) * 128 + chko];
            #pragma unroll
            for (int j = 0; j < 4; j++)
                bfr[j] = *(const bf16x8*)&Bs[(j * 16 + col) * 128 + chko];
            #pragma unroll
            for (int i = 0; i < 2; i++)
                #pragma unroll
                for (int j = 0; j < 4; j++)
                    acc[i][j] = __builtin_amdgcn_mfma_f32_16x16x32_bf16(af[i], bfr[j], acc[i][j], 0, 0, 0);
        }
        __syncthreads();
    }

    #pragma unroll
    for (int i = 0; i < 2; i++) {
        int row = m0 + wave * 32 + i * 16 + quad * 4;
        #pragma unroll
        for (int j = 0; j < 4; j++) {
            int c = n0 + j * 16 + col;
            #pragma unroll
            for (int r = 0; r < 4; r++)
                C[(size_t)(row + r) * N + c] = acc[i][j][r];
        }
    }
}

// ---------------- flash attention (32-s-tile, K/V double-buffered, counted prefetch) -----------
__global__ __launch_bounds__(256) void k_attn(const unsigned short* __restrict__ qh,
                                              const unsigned short* __restrict__ kh,
                                              const unsigned short* __restrict__ vT,
                                              unsigned short* __restrict__ enc) {
    __shared__ unsigned short Ks[2][32 * 256];
    __shared__ unsigned short Vs[2][256 * 32];
    __shared__ unsigned short Pl[4][16 * 40];

    const int tid = threadIdx.x;
    const int wave = tid >> 6, lane = tid & 63;
    const int col = lane & 15, quad = lane >> 4;
    const int kk = blockIdx.x;
    const int t0b = blockIdx.y * 32;
    const int headSel = wave & 1, rowSel = wave >> 1;
    const int n = kk * 2 + headSel;
    const int tw = t0b + rowSel * 16;

    const unsigned short* qp = qh + ((size_t)n * T_SEQ + tw) * HD;
    const unsigned short* kp = kh + (size_t)kk * T_SEQ * HD;
    const unsigned short* vp = vT + (size_t)kk * HD * T_SEQ;

    bf16x8 qf[8];
    #pragma unroll
    for (int c = 0; c < 8; c++)
        qf[c] = *(const bf16x8*)(qp + (size_t)col * HD + c * 32 + quad * 8);

    int preK[4], preV[4], ldsKo[4], ldsVo[4];
    #pragma unroll
    for (int i = 0; i < 4; i++) {
        int krow = 2 * (wave * 4 + i) + (lane >> 5);
        int kpos = lane & 31;
        preK[i] = krow * HD + ((kpos ^ (krow & 7)) * 8);
        ldsKo[i] = (wave * 4 + i) * 512;
        int vh2 = (wave * 4 + i) * 16 + (lane >> 2);
        int vpp = lane & 3;
        preV[i] = vh2 * T_SEQ + ((vpp ^ (vh2 & 3)) * 8);
        ldsVo[i] = (wave * 4 + i) * 512;
    }

    f32x4 o[16];
    #pragma unroll
    for (int h = 0; h < 16; h++) o[h] = (f32x4){0.f, 0.f, 0.f, 0.f};
    float lsum[4] = {0.f, 0.f, 0.f, 0.f};

    int s_begin = t0b - (WINDOW - 1);
    if (s_begin < 0) s_begin = 0;
    s_begin &= ~31;
    const int s_end = t0b + 32;

    // prologue: stage first tile into buf 0
    #pragma unroll
    for (int i = 0; i < 4; i++)
        gl_lds16(kp + (size_t)s_begin * HD + preK[i], &Ks[0][ldsKo[i]]);
    #pragma unroll
    for (int i = 0; i < 4; i++)
        gl_lds16(vp + (size_t)s_begin + preV[i], &Vs[0][ldsVo[i]]);
    __syncthreads();

    int nb = 0;
    for (int s0 = s_begin; s0 < s_end; s0 += 32) {
        // issue next tile's stage into the other buffer (overlaps with this compute)
        int s1 = s0 + 32;
        if (s1 < s_end) {
            #pragma unroll
            for (int i = 0; i < 4; i++)
                gl_lds16(kp + (size_t)s1 * HD + preK[i], &Ks[nb ^ 1][ldsKo[i]]);
            #pragma unroll
            for (int i = 0; i < 4; i++)
                gl_lds16(vp + (size_t)s1 + preV[i], &Vs[nb ^ 1][ldsVo[i]]);
        }
        __builtin_amdgcn_sched_barrier(0);   // keep stage issue ahead of compute

        f32x4 S0 = (f32x4){0.f, 0.f, 0.f, 0.f};
        f32x4 S1 = (f32x4){0.f, 0.f, 0.f, 0.f};
        #pragma unroll
        for (int c = 0; c < 8; c++) {
            bf16x8 kf = *(const bf16x8*)&Ks[nb][(size_t)col * HD + (((c * 4 + quad) ^ (col & 7)) * 8)];
            S0 = __builtin_amdgcn_mfma_f32_16x16x32_bf16(qf[c], kf, S0, 0, 0, 0);
        }
        #pragma unroll
        for (int c = 0; c < 8; c++) {
            bf16x8 kf = *(const bf16x8*)&Ks[nb][(size_t)(16 + col) * HD + (((c * 4 + quad) ^ (col & 7)) * 8)];
            S1 = __builtin_amdgcn_mfma_f32_16x16x32_bf16(qf[c], kf, S1, 0, 0, 0);
        }

        #pragma unroll
        for (int r = 0; r < 4; r++) {
            int t = tw + quad * 4 + r;
            int sA = s0 + col, sB = sA + 16;
            bool vA = (sA <= t) && (sA >= t - (WINDOW - 1));
            bool vB = (sB <= t) && (sB >= t - (WINDOW - 1));
            float eA = __expf(S0[r] * (2.0f / SOFT_CAP));
            float eB = __expf(S1[r] * (2.0f / SOFT_CAP));
            float rA = __builtin_amdgcn_rcpf(eA + 1.0f);
            float rB = __builtin_amdgcn_rcpf(eB + 1.0f);
            float pA = __expf(SOFT_CAP - 2.0f * SOFT_CAP * rA);
            float pB = __expf(SOFT_CAP - 2.0f * SOFT_CAP * rB);
            pA = vA ? pA : 0.0f;
            pB = vB ? pB : 0.0f;
            lsum[r] += pA + pB;
            Pl[wave][(quad * 4 + r) * 40 + col] = f2bf(pA);
            Pl[wave][(quad * 4 + r) * 40 + 16 + col] = f2bf(pB);
        }

        bf16x8 pf = *(const bf16x8*)&Pl[wave][col * 40 + quad * 8];

        #pragma unroll
        for (int ht = 0; ht < 16; ht++) {
            int h = ht * 16 + col;
            bf16x8 vf = *(const bf16x8*)&Vs[nb][(size_t)h * 32 + ((quad ^ (h & 3)) * 8)];
            o[ht] = __builtin_amdgcn_mfma_f32_16x16x32_bf16(pf, vf, o[ht], 0, 0, 0);
        }
        __syncthreads();   // drains vmcnt(0): next tile landed; publishes across waves
        nb ^= 1;
    }

    #pragma unroll
    for (int r = 0; r < 4; r++) {
        #pragma unroll
        for (int m = 1; m < 16; m <<= 1)
            lsum[r] += __shfl_xor(lsum[r], m, 16);
        lsum[r] = 1.0f / lsum[r];
    }
    #pragma unroll
    for (int ht = 0; ht < 16; ht++) {
        #pragma unroll
        for (int r = 0; r < 4; r++) {
            int t = tw + quad * 4 + r;
            enc[(size_t)t * (NQ * HD) + n * HD + ht * 16 + col] = f2bf(o[ht][r] * lsum[r]);
        }
    }
}

extern "C" void kernel_launch(void* const* d_in, const int* in_sizes, int n_in,
                              void* d_out, int out_size, void* d_ws, size_t ws_size,
                              hipStream_t stream) {
    const float* x       = (const float*)d_in[0];
    const int*   spos    = (const int*)d_in[1];
    const float* w_q     = (const float*)d_in[3];
    const float* w_kv    = (const float*)d_in[4];
    const float* w_out   = (const float*)d_in[5];
    const float* q_scale = (const float*)d_in[6];
    const float* k_scale = (const float*)d_in[7];
    float* out = (float*)d_out;

    char* ws = (char*)d_ws;
    unsigned short* xb     = (unsigned short*)(ws + 0);          // 2048x3072 bf16 (dead after gemm1)
    unsigned short* wT     = (unsigned short*)(ws + 12582912);   // 8192x3072 bf16 [12.58,62.9 MB)
    unsigned short* wToutb = (unsigned short*)(ws + 12582912);   // 3072x4096 bf16 (reuse, post-gemm1)
    unsigned short* encb   = (unsigned short*)(ws + 37748736);   // 2048x4096 bf16 (reuse, post-gemm1)
    float2*         trig   = (float2*)(ws + 62914560);           // 2048x128 float2 (old qkv region, free)
    unsigned short* qh     = (unsigned short*)(ws + 96468992);   // 16x2048x256 bf16
    unsigned short* kh     = (unsigned short*)(ws + 113246208);  // 8x2048x256 bf16
    unsigned short* vT     = (unsigned short*)(ws + 121634816);  // 8x256x2048 bf16

    k_convert<<<dim3((T_SEQ * D_MODEL / 4 + 255) / 256), dim3(256), 0, stream>>>(
        x, xb, T_SEQ * D_MODEL / 4);
    k_transpose_bf16<<<dim3(HD / 64, D_MODEL / 64, NQ), dim3(256), 0, stream>>>(
        w_q, wT, D_MODEL, HD);
    k_transpose_bf16<<<dim3(HD / 64, D_MODEL / 64, 16), dim3(256), 0, stream>>>(
        w_kv, wT + (size_t)4096 * D_MODEL, D_MODEL, HD);
    k_trig<<<dim3(T_SEQ), dim3(128), 0, stream>>>(spos, trig);
    k_gemm1<<<dim3((T_SEQ / 128) * (QKV_COLS / 256)), dim3(256), 0, stream>>>(
        xb, wT, trig, q_scale, k_scale, qh, kh, vT, T_SEQ, QKV_COLS, D_MODEL);
    k_transpose_bf16<<<dim3(D_MODEL / 64, 4096 / 64, 1), dim3(256), 0, stream>>>(
        w_out, wToutb, 4096, D_MODEL);
    k_attn<<<dim3(NKV, T_SEQ / 32), dim3(256), 0, stream>>>(qh, kh, vT, encb);
    k_gemm2<<<dim3((T_SEQ / 128) * (D_MODEL / 64)), dim3(256), 0, stream>>>(
        encb, wToutb, out, T_SEQ, D_MODEL, NQ * HD);
}

// Round 6
// 454.567 us; speedup vs baseline: 1.0444x; 1.0444x over previous
//
#include <hip/hip_runtime.h>
#include <math.h>

// Problem constants
#define T_SEQ 2048
#define D_MODEL 3072
#define NQ 16
#define NKV 8
#define HD 256
#define NHEADS_TOT 32
#define QKV_COLS 8192
#define SOFT_CAP 50.0f
#define WINDOW 1024
#define K_MASK -2.3819763e38f

typedef __attribute__((ext_vector_type(8))) short bf16x8;
typedef __attribute__((ext_vector_type(4))) float f32x4;

__device__ __forceinline__ unsigned short f2bf(float f) {
    union { float f; unsigned u; } v; v.f = f;
    unsigned r = (v.u + 0x7fff + ((v.u >> 16) & 1)) >> 16;
    return (unsigned short)r;
}
__device__ __forceinline__ float bf2f(unsigned short u) {
    union { unsigned u; float f; } v; v.u = ((unsigned)u) << 16;
    return v.f;
}

__device__ __forceinline__ void gl_lds16(const unsigned short* g, unsigned short* l) {
    __builtin_amdgcn_global_load_lds(
        (const __attribute__((address_space(1))) void*)g,
        (__attribute__((address_space(3))) void*)l, 16, 0, 0);
}

// ---------------- convert f32 -> bf16 (flat) ----------------
__global__ __launch_bounds__(256) void k_convert(const float* __restrict__ src,
                                                 unsigned short* __restrict__ dst, int n4) {
    int i = blockIdx.x * 256 + threadIdx.x;
    if (i >= n4) return;
    float4 v = ((const float4*)src)[i];
    ushort4 o;
    o.x = f2bf(v.x); o.y = f2bf(v.y); o.z = f2bf(v.z); o.w = f2bf(v.w);
    ((ushort4*)dst)[i] = o;
}

// ---------------- batched transpose+convert v2: (batch,R,C) f32 -> (batch,C,R) bf16 --------
__global__ __launch_bounds__(256) void k_transpose_bf16(const float* __restrict__ src,
                                                        unsigned short* __restrict__ dst,
                                                        int R, int C) {
    __shared__ unsigned short T[64][68];   // [src-col][src-row], pad 4 to break banks
    int b = blockIdx.z;
    src += (size_t)b * R * C;
    dst += (size_t)b * R * C;
    int c0 = blockIdx.x * 64, r0 = blockIdx.y * 64;
    int tid = threadIdx.x;
    int wv = tid >> 6, ln = tid & 63;
    int rsub = (wv << 2) + (ln >> 4);      // 0..15
    int cq = (ln & 15) << 2;               // 0,4,...,60
    #pragma unroll
    for (int p = 0; p < 4; p++) {
        int row = p * 16 + rsub;
        float4 v = *(const float4*)&src[(size_t)(r0 + row) * C + c0 + cq];
        T[cq + 0][row] = f2bf(v.x);
        T[cq + 1][row] = f2bf(v.y);
        T[cq + 2][row] = f2bf(v.z);
        T[cq + 3][row] = f2bf(v.w);
    }
    __syncthreads();
    #pragma unroll
    for (int q = 0; q < 4; q++) {
        int crow = q * 16 + rsub;          // output row = global col c0+crow
        ushort4 o = *(const ushort4*)&T[crow][cq];
        *(ushort4*)&dst[(size_t)(c0 + crow) * R + r0 + cq] = o;
    }
}

// ---------------- RoPE trig table: (T, 128) float2 {sin, cos} ----------------
__global__ __launch_bounds__(128) void k_trig(const int* __restrict__ spos,
                                              float2* __restrict__ tbl) {
    int t = blockIdx.x, hh = threadIdx.x;
    float fr = (float)hh * (1.0f / 128.0f);
    float ts = __expf(fr * 9.210340371976184f);   // 10000^fr
    float ang = (float)spos[t] / ts;
    float2 sc;
    sc.x = __sinf(ang);
    sc.y = __cosf(ang);
    tbl[(size_t)t * 128 + hh] = sc;
}

// ---------------- gemm1 + fused RMS-norm/RoPE/V-transpose epilogue (R6: lane-local pairs) -----
// C = A * BT^T over 128x256 tiles; block cols = one head slot (slot = n0>>8: 0-15 q,
// 16-23 k, 24-31 v).  R6 fix for R5's 917K bank conflicts: the RoPE pair (h, h+128) is
// made LANE-LOCAL by remapping the wave->column assignment,
//     bcol(j) = wc*64 + (j>>1)*16 + (j&1)*128 + col
// (j even holds h, j odd holds h+128).  Pure permutation: swizzle structure unchanged
// (bcol&7 == col&7), RMS-norm is permutation-invariant (cross-wave combine via rs[] in
// dead As), C-write targets n0+bcol.  RoPE = 2 in-reg FMAs + ONE trig load per pair.
// The entire yb LDS exchange (8 barriers, 4-way-conflicted f32 traffic) is deleted.
__global__ __launch_bounds__(256, 2) void k_gemm1(const unsigned short* __restrict__ A,
                                                  const unsigned short* __restrict__ BT,
                                                  const float2* __restrict__ trig,
                                                  const float* __restrict__ qscale,
                                                  const float* __restrict__ kscale,
                                                  unsigned short* __restrict__ qh,
                                                  unsigned short* __restrict__ kh,
                                                  unsigned short* __restrict__ vT,
                                                  int M, int N, int Kd) {
    __shared__ unsigned short As[128 * 64];   // 16 KB
    __shared__ unsigned short Bs[256 * 64];   // 32 KB
    const int tid = threadIdx.x;
    const int wave = tid >> 6, lane = tid & 63;
    const int col = lane & 15, quad = lane >> 4;
    const int wr = wave & 1, wc = wave >> 1;

    int p = blockIdx.x;                 // 512 blocks
    int xcd = p & 7, q = p >> 3;        // q in [0,64)
    int i_t = q & 15, jj = q >> 4;      // i in [0,16), jj in [0,4)
    const int m0 = i_t * 128, n0 = (jj * 8 + xcd) * 256;

    const int lrow = lane >> 3, lchk = lane & 7;
    int soffA[4], soffB[8];
    #pragma unroll
    for (int s = 0; s < 4; s++) {
        int r = wave * 32 + s * 8 + lrow;
        soffA[s] = r * Kd + ((lchk ^ (r & 7)) * 8);
    }
    #pragma unroll
    for (int s = 0; s < 8; s++) {
        int r = wave * 64 + s * 8 + lrow;
        soffB[s] = r * Kd + ((lchk ^ (r & 7)) * 8);
    }
    const unsigned short* Ab = A + (size_t)m0 * Kd;
    const unsigned short* Bb = BT + (size_t)n0 * Kd;

    f32x4 acc[4][8];
    #pragma unroll
    for (int i = 0; i < 4; i++)
        #pragma unroll
        for (int j = 0; j < 8; j++)
            acc[i][j] = (f32x4){0.f, 0.f, 0.f, 0.f};

    const int sw = col & 7;

    for (int k0 = 0; k0 < Kd; k0 += 64) {
        #pragma unroll
        for (int s = 0; s < 4; s++)
            gl_lds16(Ab + soffA[s] + k0, &As[(wave * 32 + s * 8) * 64]);
        #pragma unroll
        for (int s = 0; s < 8; s++)
            gl_lds16(Bb + soffB[s] + k0, &Bs[(wave * 64 + s * 8) * 64]);
        __syncthreads();

        #pragma unroll
        for (int kk = 0; kk < 2; kk++) {
            const int chko = ((kk * 4 + quad) ^ sw) * 8;
            bf16x8 af[4];
            #pragma unroll
            for (int i = 0; i < 4; i++)
                af[i] = *(const bf16x8*)&As[(wr * 64 + i * 16 + col) * 64 + chko];
            #pragma unroll
            for (int j = 0; j < 8; j++) {
                // lane-local RoPE-pair column map (see header comment)
                const int bcol = wc * 64 + (j >> 1) * 16 + (j & 1) * 128 + col;
                bf16x8 bfr = *(const bf16x8*)&Bs[bcol * 64 + chko];
                #pragma unroll
                for (int i = 0; i < 4; i++)
                    acc[i][j] = __builtin_amdgcn_mfma_f32_16x16x32_bf16(af[i], bfr, acc[i][j], 0, 0, 0);
            }
        }
        __syncthreads();
    }

    // ================= fused epilogue (no LDS exchange) =================
    const int slot = n0 >> 8;              // block-uniform: 0-15 q, 16-23 k, 24-31 v
    float* rs = (float*)As;                // [2][128] row sums per wave-half

    // (a) per-row sum of squares: lane partial (8 cols) -> 16-lane col-group reduce
    float rinv[4][4];
    #pragma unroll
    for (int i = 0; i < 4; i++)
        #pragma unroll
        for (int r = 0; r < 4; r++) {
            float ss = 0.f;
            #pragma unroll
            for (int j = 0; j < 8; j++) ss += acc[i][j][r] * acc[i][j][r];
            #pragma unroll
            for (int m = 1; m < 16; m <<= 1) ss += __shfl_xor(ss, m, 16);
            if (col == 0) rs[wc * 128 + wr * 64 + i * 16 + quad * 4 + r] = ss;
        }
    __syncthreads();
    #pragma unroll
    for (int i = 0; i < 4; i++)
        #pragma unroll
        for (int r = 0; r < 4; r++) {
            int rl = wr * 64 + i * 16 + quad * 4 + r;
            float tot = rs[rl] + rs[128 + rl];
            rinv[i][r] = rsqrtf(tot * (1.0f / 256.0f) + 1e-6f);
        }

    // (b) per-col scale factor (at the actual column bcol(j))
    float scl[8];
    #pragma unroll
    for (int j = 0; j < 8; j++) {
        int h = wc * 64 + (j >> 1) * 16 + (j & 1) * 128 + col;
        scl[j] = (slot < 16) ? (1.0f + qscale[h])
               : (slot < 24) ? (1.0f + kscale[h]) : 1.0f;
    }

    // (c) rope in-register on the (j even, j odd) pair; one trig load per pair
    #pragma unroll
    for (int i = 0; i < 4; i++) {
        #pragma unroll
        for (int jp = 0; jp < 4; jp++) {
            int h = wc * 64 + jp * 16 + col;       // in [0,128)
            #pragma unroll
            for (int r = 0; r < 4; r++) {
                int t = m0 + wr * 64 + i * 16 + quad * 4 + r;
                float e = acc[i][2 * jp][r]     * rinv[i][r] * scl[2 * jp];
                float o = acc[i][2 * jp + 1][r] * rinv[i][r] * scl[2 * jp + 1];
                float oe, oo;
                if (slot < 24) {
                    float2 sc = trig[(size_t)t * 128 + h];
                    oe = e * sc.y - o * sc.x;
                    oo = o * sc.y + e * sc.x;
                } else {
                    oe = e; oo = o;
                }
                if (slot < 16) {
                    size_t base = ((size_t)slot * T_SEQ + t) * HD + h;
                    qh[base]       = f2bf(oe);
                    qh[base + 128] = f2bf(oo);
                } else if (slot < 24) {
                    size_t base = ((size_t)(slot - 16) * T_SEQ + t) * HD + h;
                    kh[base]       = f2bf(oe);
                    kh[base + 128] = f2bf(oo);
                } else {
                    vT[((size_t)(slot - 24) * HD + h) * T_SEQ + t]         = f2bf(oe);
                    vT[((size_t)(slot - 24) * HD + h + 128) * T_SEQ + t]   = f2bf(oo);
                }
            }
        }
    }
}

// ---------------- gemm2: 128x64 tile, BK=128 (32 barriers), 768 blocks, f32 out ----------------
__global__ __launch_bounds__(256) void k_gemm2(const unsigned short* __restrict__ A,
                                               const unsigned short* __restrict__ BT,
                                               float* __restrict__ C,
                                               int M, int N, int Kd) {
    __shared__ unsigned short As[128 * 128];  // 32 KB
    __shared__ unsigned short Bs[64 * 128];   // 16 KB
    const int tid = threadIdx.x;
    const int wave = tid >> 6, lane = tid & 63;
    const int col = lane & 15, quad = lane >> 4;

    int p = blockIdx.x;                    // 768 blocks
    int xcd = p & 7, q = p >> 3;           // q in [0,96)
    int i_t = q % 16, jj = q / 16;         // jj in [0,6)
    const int m0 = i_t * 128, n0 = (jj * 8 + xcd) * 64;

    const int lrow = lane >> 4, lchk = lane & 15;
    int soffA[8], soffB[4];
    #pragma unroll
    for (int s = 0; s < 8; s++) {
        int r = wave * 32 + s * 4 + lrow;
        soffA[s] = r * Kd + ((lchk ^ (r & 7)) * 8);
    }
    #pragma unroll
    for (int s = 0; s < 4; s++) {
        int r = wave * 16 + s * 4 + lrow;
        soffB[s] = r * Kd + ((lchk ^ (r & 7)) * 8);
    }
    const unsigned short* Ab = A + (size_t)m0 * Kd;
    const unsigned short* Bb = BT + (size_t)n0 * Kd;

    f32x4 acc[2][4];
    #pragma unroll
    for (int i = 0; i < 2; i++)
        #pragma unroll
        for (int j = 0; j < 4; j++)
            acc[i][j] = (f32x4){0.f, 0.f, 0.f, 0.f};

    const int sw = col & 7;

    for (int k0 = 0; k0 < Kd; k0 += 128) {
        #pragma unroll
        for (int s = 0; s < 8; s++)
            gl_lds16(Ab + soffA[s] + k0, &As[(wave * 32 + s * 4) * 128]);
        #pragma unroll
        for (int s = 0; s < 4; s++)
            gl_lds16(Bb + soffB[s] + k0, &Bs[(wave * 16 + s * 4) * 128]);
        __syncthreads();

        #pragma unroll
        for (int kk = 0; kk < 4; kk++) {
            const int chko = ((kk * 4 + quad) ^ sw) * 8;
            bf16x8 af[2], bfr[4];
            #pragma unroll
            for (int i = 0; i < 2; i++)
                af[i] = *(const bf16x8*)&As[(wave * 32 + i * 16 + col) * 128 + chko];
            #pragma unroll
            for (int j = 0; j < 4; j++)
                bfr[j] = *(const bf16x8*)&Bs[(j * 16 + col) * 128 + chko];
            #pragma unroll
            for (int i = 0; i < 2; i++)
                #pragma unroll
                for (int j = 0; j < 4; j++)
                    acc[i][j] = __builtin_amdgcn_mfma_f32_16x16x32_bf16(af[i], bfr[j], acc[i][j], 0, 0, 0);
        }
        __syncthreads();
    }

    #pragma unroll
    for (int i = 0; i < 2; i++) {
        int row = m0 + wave * 32 + i * 16 + quad * 4;
        #pragma unroll
        for (int j = 0; j < 4; j++) {
            int c = n0 + j * 16 + col;
            #pragma unroll
            for (int r = 0; r < 4; r++)
                C[(size_t)(row + r) * N + c] = acc[i][j][r];
        }
    }
}

// ---------------- flash attention (32-s-tile, K/V double-buffered, counted prefetch) -----------
__global__ __launch_bounds__(256) void k_attn(const unsigned short* __restrict__ qh,
                                              const unsigned short* __restrict__ kh,
                                              const unsigned short* __restrict__ vT,
                                              unsigned short* __restrict__ enc) {
    __shared__ unsigned short Ks[2][32 * 256];
    __shared__ unsigned short Vs[2][256 * 32];
    __shared__ unsigned short Pl[4][16 * 40];

    const int tid = threadIdx.x;
    const int wave = tid >> 6, lane = tid & 63;
    const int col = lane & 15, quad = lane >> 4;
    const int kk = blockIdx.x;
    const int t0b = blockIdx.y * 32;
    const int headSel = wave & 1, rowSel = wave >> 1;
    const int n = kk * 2 + headSel;
    const int tw = t0b + rowSel * 16;

    const unsigned short* qp = qh + ((size_t)n * T_SEQ + tw) * HD;
    const unsigned short* kp = kh + (size_t)kk * T_SEQ * HD;
    const unsigned short* vp = vT + (size_t)kk * HD * T_SEQ;

    bf16x8 qf[8];
    #pragma unroll
    for (int c = 0; c < 8; c++)
        qf[c] = *(const bf16x8*)(qp + (size_t)col * HD + c * 32 + quad * 8);

    int preK[4], preV[4], ldsKo[4], ldsVo[4];
    #pragma unroll
    for (int i = 0; i < 4; i++) {
        int krow = 2 * (wave * 4 + i) + (lane >> 5);
        int kpos = lane & 31;
        preK[i] = krow * HD + ((kpos ^ (krow & 7)) * 8);
        ldsKo[i] = (wave * 4 + i) * 512;
        int vh2 = (wave * 4 + i) * 16 + (lane >> 2);
        int vpp = lane & 3;
        preV[i] = vh2 * T_SEQ + ((vpp ^ (vh2 & 3)) * 8);
        ldsVo[i] = (wave * 4 + i) * 512;
    }

    f32x4 o[16];
    #pragma unroll
    for (int h = 0; h < 16; h++) o[h] = (f32x4){0.f, 0.f, 0.f, 0.f};
    float lsum[4] = {0.f, 0.f, 0.f, 0.f};

    int s_begin = t0b - (WINDOW - 1);
    if (s_begin < 0) s_begin = 0;
    s_begin &= ~31;
    const int s_end = t0b + 32;

    // prologue: stage first tile into buf 0
    #pragma unroll
    for (int i = 0; i < 4; i++)
        gl_lds16(kp + (size_t)s_begin * HD + preK[i], &Ks[0][ldsKo[i]]);
    #pragma unroll
    for (int i = 0; i < 4; i++)
        gl_lds16(vp + (size_t)s_begin + preV[i], &Vs[0][ldsVo[i]]);
    __syncthreads();

    int nb = 0;
    for (int s0 = s_begin; s0 < s_end; s0 += 32) {
        // issue next tile's stage into the other buffer (overlaps with this compute)
        int s1 = s0 + 32;
        if (s1 < s_end) {
            #pragma unroll
            for (int i = 0; i < 4; i++)
                gl_lds16(kp + (size_t)s1 * HD + preK[i], &Ks[nb ^ 1][ldsKo[i]]);
            #pragma unroll
            for (int i = 0; i < 4; i++)
                gl_lds16(vp + (size_t)s1 + preV[i], &Vs[nb ^ 1][ldsVo[i]]);
        }
        __builtin_amdgcn_sched_barrier(0);   // keep stage issue ahead of compute

        f32x4 S0 = (f32x4){0.f, 0.f, 0.f, 0.f};
        f32x4 S1 = (f32x4){0.f, 0.f, 0.f, 0.f};
        #pragma unroll
        for (int c = 0; c < 8; c++) {
            bf16x8 kf = *(const bf16x8*)&Ks[nb][(size_t)col * HD + (((c * 4 + quad) ^ (col & 7)) * 8)];
            S0 = __builtin_amdgcn_mfma_f32_16x16x32_bf16(qf[c], kf, S0, 0, 0, 0);
        }
        #pragma unroll
        for (int c = 0; c < 8; c++) {
            bf16x8 kf = *(const bf16x8*)&Ks[nb][(size_t)(16 + col) * HD + (((c * 4 + quad) ^ (col & 7)) * 8)];
            S1 = __builtin_amdgcn_mfma_f32_16x16x32_bf16(qf[c], kf, S1, 0, 0, 0);
        }

        #pragma unroll
        for (int r = 0; r < 4; r++) {
            int t = tw + quad * 4 + r;
            int sA = s0 + col, sB = sA + 16;
            bool vA = (sA <= t) && (sA >= t - (WINDOW - 1));
            bool vB = (sB <= t) && (sB >= t - (WINDOW - 1));
            float eA = __expf(S0[r] * (2.0f / SOFT_CAP));
            float eB = __expf(S1[r] * (2.0f / SOFT_CAP));
            float rA = __builtin_amdgcn_rcpf(eA + 1.0f);
            float rB = __builtin_amdgcn_rcpf(eB + 1.0f);
            float pA = __expf(SOFT_CAP - 2.0f * SOFT_CAP * rA);
            float pB = __expf(SOFT_CAP - 2.0f * SOFT_CAP * rB);
            pA = vA ? pA : 0.0f;
            pB = vB ? pB : 0.0f;
            lsum[r] += pA + pB;
            Pl[wave][(quad * 4 + r) * 40 + col] = f2bf(pA);
            Pl[wave][(quad * 4 + r) * 40 + 16 + col] = f2bf(pB);
        }

        bf16x8 pf = *(const bf16x8*)&Pl[wave][col * 40 + quad * 8];

        #pragma unroll
        for (int ht = 0; ht < 16; ht++) {
            int h = ht * 16 + col;
            bf16x8 vf = *(const bf16x8*)&Vs[nb][(size_t)h * 32 + ((quad ^ (h & 3)) * 8)];
            o[ht] = __builtin_amdgcn_mfma_f32_16x16x32_bf16(pf, vf, o[ht], 0, 0, 0);
        }
        __syncthreads();   // drains vmcnt(0): next tile landed; publishes across waves
        nb ^= 1;
    }

    #pragma unroll
    for (int r = 0; r < 4; r++) {
        #pragma unroll
        for (int m = 1; m < 16; m <<= 1)
            lsum[r] += __shfl_xor(lsum[r], m, 16);
        lsum[r] = 1.0f / lsum[r];
    }
    #pragma unroll
    for (int ht = 0; ht < 16; ht++) {
        #pragma unroll
        for (int r = 0; r < 4; r++) {
            int t = tw + quad * 4 + r;
            enc[(size_t)t * (NQ * HD) + n * HD + ht * 16 + col] = f2bf(o[ht][r] * lsum[r]);
        }
    }
}

extern "C" void kernel_launch(void* const* d_in, const int* in_sizes, int n_in,
                              void* d_out, int out_size, void* d_ws, size_t ws_size,
                              hipStream_t stream) {
    const float* x       = (const float*)d_in[0];
    const int*   spos    = (const int*)d_in[1];
    const float* w_q     = (const float*)d_in[3];
    const float* w_kv    = (const float*)d_in[4];
    const float* w_out   = (const float*)d_in[5];
    const float* q_scale = (const float*)d_in[6];
    const float* k_scale = (const float*)d_in[7];
    float* out = (float*)d_out;

    char* ws = (char*)d_ws;
    unsigned short* xb     = (unsigned short*)(ws + 0);          // 2048x3072 bf16 (dead after gemm1)
    unsigned short* wT     = (unsigned short*)(ws + 12582912);   // 8192x3072 bf16 [12.58,62.9 MB)
    unsigned short* wToutb = (unsigned short*)(ws + 12582912);   // 3072x4096 bf16 (reuse, post-gemm1)
    unsigned short* encb   = (unsigned short*)(ws + 37748736);   // 2048x4096 bf16 (reuse, post-gemm1)
    float2*         trig   = (float2*)(ws + 62914560);           // 2048x128 float2
    unsigned short* qh     = (unsigned short*)(ws + 96468992);   // 16x2048x256 bf16
    unsigned short* kh     = (unsigned short*)(ws + 113246208);  // 8x2048x256 bf16
    unsigned short* vT     = (unsigned short*)(ws + 121634816);  // 8x256x2048 bf16

    k_convert<<<dim3((T_SEQ * D_MODEL / 4 + 255) / 256), dim3(256), 0, stream>>>(
        x, xb, T_SEQ * D_MODEL / 4);
    k_transpose_bf16<<<dim3(HD / 64, D_MODEL / 64, NQ), dim3(256), 0, stream>>>(
        w_q, wT, D_MODEL, HD);
    k_transpose_bf16<<<dim3(HD / 64, D_MODEL / 64, 16), dim3(256), 0, stream>>>(
        w_kv, wT + (size_t)4096 * D_MODEL, D_MODEL, HD);
    k_trig<<<dim3(T_SEQ), dim3(128), 0, stream>>>(spos, trig);
    k_gemm1<<<dim3((T_SEQ / 128) * (QKV_COLS / 256)), dim3(256), 0, stream>>>(
        xb, wT, trig, q_scale, k_scale, qh, kh, vT, T_SEQ, QKV_COLS, D_MODEL);
    k_transpose_bf16<<<dim3(D_MODEL / 64, 4096 / 64, 1), dim3(256), 0, stream>>>(
        w_out, wToutb, 4096, D_MODEL);
    k_attn<<<dim3(NKV, T_SEQ / 32), dim3(256), 0, stream>>>(qh, kh, vT, encb);
    k_gemm2<<<dim3((T_SEQ / 128) * (D_MODEL / 64)), dim3(256), 0, stream>>>(
        encb, wToutb, out, T_SEQ, D_MODEL, NQ * HD);
}